// Round 2
// baseline (532.786 us; speedup 1.0000x reference)
//
#include <hip/hip_runtime.h>
#include <cstdint>
#include <cstddef>

#define DEVFN __device__ __forceinline__

typedef __attribute__((ext_vector_type(8))) __bf16 bf16x8;
typedef __attribute__((ext_vector_type(4))) float f32x4;

static constexpr int DM = 1024;
static constexpr int NH = 16;
static constexpr int HD = 64;
static constexpr int BATCH = 512;
static constexpr int SEQ = 64;
static constexpr int MROWS = BATCH * SEQ;   // 32768
static constexpr int KDIM = DM;             // 1024
static constexpr int BK = 64;
static constexpr int NT = KDIM / BK;        // 16 k-tiles

DEVFN unsigned short f2bf(float f) {
  unsigned u = __builtin_bit_cast(unsigned, f);
  u += 0x7fffu + ((u >> 16) & 1u);   // RNE
  return (unsigned short)(u >> 16);
}

DEVFN void gload_lds16(const void* g, void* l) {
  // async global->LDS, 16B per lane; LDS dest = wave-uniform base + lane*16B
  __builtin_amdgcn_global_load_lds(
      (__attribute__((address_space(1))) const void*)g,
      (__attribute__((address_space(3))) void*)l, 16, 0, 0);
}

// ---------------- fp32 -> bf16 convert (grid-stride, float4 loads) ----------
__global__ void convert_kernel(const float* __restrict__ src,
                               unsigned short* __restrict__ dst, int n) {
  int i = (blockIdx.x * blockDim.x + threadIdx.x) * 4;
  const int stride = gridDim.x * blockDim.x * 4;
  for (; i < n; i += stride) {
    float4 f = *reinterpret_cast<const float4*>(src + i);
    ushort4 o;
    o.x = f2bf(f.x); o.y = f2bf(f.y); o.z = f2bf(f.z); o.w = f2bf(f.w);
    *reinterpret_cast<ushort4*>(dst + i) = o;
  }
}

// ---------------- RoPE cos/sin table: [SEQ][512] float2 ---------------------
__global__ void rope_table_kernel(float2* __restrict__ tab) {
  int idx = blockIdx.x * blockDim.x + threadIdx.x;
  if (idx >= SEQ * 512) return;
  int s = idx >> 9, i = idx & 511;
  float inv_freq = exp2f(-(float)i * (13.287712379549449f / 512.0f));
  float ang = (float)s * inv_freq;
  tab[idx] = make_float2(cosf(ang), sinf(ang));
}

// ---------------- 256x256 GEMM, BK=64, 8 waves, counted-vmcnt pipeline ------
// C[M][N] = A[M][K] * B[N][K]^T (+epilogue)
// MODE 0: QKV projection (N=3072): bias + RoPE on q,k; bf16 scatter to
//         q/k/v buffers [B][H][S][HD].
// MODE 1: O projection (N=1024): +bias, fp32 store.
// LDS swizzle (T2): byte_in_row ^= (row&7)<<4, applied on the pre-swizzled
// global source (global_load_lds writes linearly) and on every ds_read.
template <int MODE>
__global__ __launch_bounds__(512, 1)
void gemm256_kernel(const unsigned short* __restrict__ A,
                    const unsigned short* __restrict__ Bw,
                    const float* __restrict__ bias0,
                    const float* __restrict__ bias1,
                    const float* __restrict__ bias2,
                    const float2* __restrict__ rope,
                    unsigned short* __restrict__ qb,
                    unsigned short* __restrict__ kb,
                    unsigned short* __restrict__ vb,
                    float* __restrict__ outf,
                    int Ntiles) {
  __shared__ __align__(16) unsigned short sA[2][256 * BK];
  __shared__ __align__(16) unsigned short sB[2][256 * BK];

  // T1: XCD-aware bijective swizzle (grid %8 == 0 in both modes)
  const int cpx = gridDim.x >> 3;
  const int bid = (blockIdx.x & 7) * cpx + (blockIdx.x >> 3);
  const int bm = bid / Ntiles, bn = bid % Ntiles;
  const int m0 = bm * 256, n0 = bn * 256;

  const int tid = threadIdx.x;
  const int wave = tid >> 6, lane = tid & 63;
  const int wr = wave >> 2, wc = wave & 3;   // 2x4 waves; 128x64 out per wave

  // ---- staging addresses (pre-swizzled global source, linear LDS dest) ----
  const int srow = tid >> 3;                         // 0..63
  const int scol = ((tid & 7) ^ (srow & 7)) * 8;     // swizzled col (ushorts)
  const unsigned short* aB = A + ((size_t)m0 + srow) * KDIM + scol;
  const unsigned short* bB = Bw + ((size_t)n0 + srow) * KDIM + scol;
  const int ldsStg = wave * 512;                     // ushorts (wave*1024 B)

  auto STAGE = [&](int buf, int t) {
    const size_t kc = (size_t)t * BK;
#pragma unroll
    for (int i = 0; i < 4; ++i) {
      gload_lds16(aB + ((size_t)i * 64) * KDIM + kc, &sA[buf][i * 4096 + ldsStg]);
      gload_lds16(bB + ((size_t)i * 64) * KDIM + kc, &sB[buf][i * 4096 + ldsStg]);
    }
  };

  // ---- compute-side LDS addresses (swizzled read) ----
  const int rA = wr * 128 + (lane & 15);   // + mi*16
  const int rB = wc * 64 + (lane & 15);    // + ni*16
  const int kq = (lane >> 4) * 8;          // k-slot base (ushorts)
  const int kx = (lane & 7) * 8;           // swizzle xor  (ushorts)

  f32x4 acc[8][4] = {};

  // prologue: tiles 0,1 in flight; wait tile0 (8 newest still flying)
  STAGE(0, 0);
  STAGE(1, 1);
  asm volatile("s_waitcnt vmcnt(8)" ::: "memory");
  __builtin_amdgcn_sched_barrier(0);
  __builtin_amdgcn_s_barrier();

  for (int t = 0; t < NT; ++t) {
    const unsigned short* bufA = sA[t & 1];
    const unsigned short* bufB = sB[t & 1];
#pragma unroll
    for (int ks = 0; ks < 2; ++ks) {
      const int koff = ((ks * 32 + kq) ^ kx);
      bf16x8 a[8], b[4];
#pragma unroll
      for (int mi = 0; mi < 8; ++mi)
        a[mi] = *reinterpret_cast<const bf16x8*>(&bufA[(rA + mi * 16) * BK + koff]);
#pragma unroll
      for (int ni = 0; ni < 4; ++ni)
        b[ni] = *reinterpret_cast<const bf16x8*>(&bufB[(rB + ni * 16) * BK + koff]);
      __builtin_amdgcn_s_setprio(1);
#pragma unroll
      for (int mi = 0; mi < 8; ++mi)
#pragma unroll
        for (int ni = 0; ni < 4; ++ni)
          acc[mi][ni] = __builtin_amdgcn_mfma_f32_16x16x32_bf16(
              a[mi], b[ni], acc[mi][ni], 0, 0, 0);
      __builtin_amdgcn_s_setprio(0);
    }
    __builtin_amdgcn_sched_barrier(0);
    __builtin_amdgcn_s_barrier();   // all waves done reading buf[t&1]
    if (t + 2 < NT) {
      STAGE(t & 1, t + 2);          // overwrite freed buffer
      asm volatile("s_waitcnt vmcnt(8)" ::: "memory");   // tile t+1 landed
    } else {
      asm volatile("s_waitcnt vmcnt(0)" ::: "memory");
    }
    __builtin_amdgcn_sched_barrier(0);
    __builtin_amdgcn_s_barrier();
  }

  // epilogue; C/D layout: col = lane&15, row = (lane>>4)*4 + r  [m89/m91]
#pragma unroll
  for (int mi = 0; mi < 8; ++mi) {
#pragma unroll
    for (int ni = 0; ni < 4; ++ni) {
#pragma unroll
      for (int r = 0; r < 4; ++r) {
        const int row = m0 + wr * 128 + mi * 16 + (lane >> 4) * 4 + r;
        const int col = n0 + wc * 64 + ni * 16 + (lane & 15);
        float v = acc[mi][ni][r];
        if (MODE == 0) {
          const int id = col >> 10;        // 0=q 1=k 2=v (wave-uniform per ni)
          const int c = col & 1023;
          const float* bp = (id == 0) ? bias0 : (id == 1 ? bias1 : bias2);
          v += bp[c];
          const int si = row & 63;
          if (id < 2) {
            // RoPE: pair (2i,2i+1) lives in lanes (l, l^1)
            const float p = __shfl_xor(v, 1);
            const float2 cs = rope[(si << 9) + (c >> 1)];
            v = v * cs.x + ((lane & 1) ? p * cs.y : -p * cs.y);
          }
          const int bi = row >> 6;
          const int h = c >> 6, dh = c & 63;
          const size_t off = (((size_t)bi * NH + h) * SEQ + si) * HD + dh;
          const unsigned short bfv = f2bf(v);
          if (id == 0) qb[off] = bfv;
          else if (id == 1) kb[off] = bfv;
          else vb[off] = bfv;
        } else {
          outf[(size_t)row * DM + col] = v + bias0[col];
        }
      }
    }
  }
}

// ---------------- attention: one block per (b,h); S=64, HD=64 ---------------
__global__ __launch_bounds__(256, 4)
void attn_kernel(const unsigned short* __restrict__ qb,
                 const unsigned short* __restrict__ kbuf,
                 const unsigned short* __restrict__ vbuf,
                 unsigned short* __restrict__ vals) {
  __shared__ __align__(16) unsigned short sQ[64 * 64];
  __shared__ __align__(16) unsigned short sK[64 * 64];
  __shared__ __align__(16) unsigned short sV[64 * 64];
  __shared__ __align__(16) unsigned short sP[64 * 64];
  const int bh = blockIdx.x;              // b*NH + h
  const int t = threadIdx.x, wave = t >> 6, lane = t & 63;
  const size_t base = (size_t)bh * 4096;

#pragma unroll
  for (int is = 0; is < 2; ++is) {
    const size_t go = base + is * 2048 + wave * 512 + (size_t)lane * 8;
    const int lo = is * 2048 + wave * 512;
    gload_lds16(qb + go, &sQ[lo]);
    gload_lds16(kbuf + go, &sK[lo]);
    gload_lds16(vbuf + go, &sV[lo]);
  }
  __syncthreads();

  // S = Q K^T : wave owns 16 q-rows; 4 col-frags cover 64 keys
  f32x4 sacc[4] = {};
#pragma unroll
  for (int kk = 0; kk < 2; ++kk) {
    const int krow = kk * 32 + (lane >> 4) * 8;
    const bf16x8 aq = *reinterpret_cast<const bf16x8*>(
        &sQ[(wave * 16 + (lane & 15)) * 64 + krow]);
#pragma unroll
    for (int ni = 0; ni < 4; ++ni) {
      const bf16x8 bkf = *reinterpret_cast<const bf16x8*>(
          &sK[(ni * 16 + (lane & 15)) * 64 + krow]);
      sacc[ni] = __builtin_amdgcn_mfma_f32_16x16x32_bf16(aq, bkf, sacc[ni], 0, 0, 0);
    }
  }
#pragma unroll
  for (int ni = 0; ni < 4; ++ni) sacc[ni] *= 0.125f;   // 1/sqrt(64)

  // softmax across 64 cols: in-lane over 4 frags, then shfl-xor over 16 lanes
#pragma unroll
  for (int r = 0; r < 4; ++r) {
    float mx = sacc[0][r];
#pragma unroll
    for (int ni = 1; ni < 4; ++ni) mx = fmaxf(mx, sacc[ni][r]);
#pragma unroll
    for (int off = 8; off; off >>= 1) mx = fmaxf(mx, __shfl_xor(mx, off));
    float e[4]; float sum = 0.f;
#pragma unroll
    for (int ni = 0; ni < 4; ++ni) { e[ni] = __expf(sacc[ni][r] - mx); sum += e[ni]; }
#pragma unroll
    for (int off = 8; off; off >>= 1) sum += __shfl_xor(sum, off);
    const float inv = 1.0f / sum;
    const int rowl = wave * 16 + (lane >> 4) * 4 + r;
#pragma unroll
    for (int ni = 0; ni < 4; ++ni)
      sP[rowl * 64 + ni * 16 + (lane & 15)] = f2bf(e[ni] * inv);
  }
  __syncthreads();

  // vals = P V
  f32x4 vacc[4] = {};
#pragma unroll
  for (int kk = 0; kk < 2; ++kk) {
    const int kb0 = kk * 32 + (lane >> 4) * 8;
    const bf16x8 ap = *reinterpret_cast<const bf16x8*>(
        &sP[(wave * 16 + (lane & 15)) * 64 + kb0]);
#pragma unroll
    for (int ni = 0; ni < 4; ++ni) {
      bf16x8 bvv;
      const int dh = ni * 16 + (lane & 15);
#pragma unroll
      for (int i = 0; i < 8; ++i)
        bvv[i] = __builtin_bit_cast(__bf16, sV[(kb0 + i) * 64 + dh]);
      vacc[ni] = __builtin_amdgcn_mfma_f32_16x16x32_bf16(ap, bvv, vacc[ni], 0, 0, 0);
    }
  }

  // store vals bf16 into [MROWS][DM] layout (row=b*64+s, col=h*64+dh)
  const int b = bh >> 4, h = bh & 15;
#pragma unroll
  for (int ni = 0; ni < 4; ++ni) {
#pragma unroll
    for (int r = 0; r < 4; ++r) {
      const int si = wave * 16 + (lane >> 4) * 4 + r;
      const int dh = ni * 16 + (lane & 15);
      vals[((size_t)b * SEQ + si) * DM + h * HD + dh] = f2bf(vacc[ni][r]);
    }
  }
}

// ---------------------------------------------------------------------------
extern "C" void kernel_launch(void* const* d_in, const int* in_sizes, int n_in,
                              void* d_out, int out_size, void* d_ws, size_t ws_size,
                              hipStream_t stream) {
  (void)in_sizes; (void)n_in; (void)out_size; (void)ws_size;
  const float* x  = (const float*)d_in[0];
  const float* Wq = (const float*)d_in[1];
  const float* bq = (const float*)d_in[2];
  const float* Wk = (const float*)d_in[3];
  const float* bk = (const float*)d_in[4];
  const float* Wv = (const float*)d_in[5];
  const float* bv = (const float*)d_in[6];
  const float* Wo = (const float*)d_in[7];
  const float* bo = (const float*)d_in[8];
  float* out = (float*)d_out;

  // ws layout (bf16 buffers), total ~277 MB
  unsigned short* xb   = (unsigned short*)d_ws;            // x bf16; later reused for vals
  unsigned short* wb   = xb + (size_t)MROWS * DM;          // Wq|Wk|Wv|Wo bf16, [4096][1024]
  unsigned short* qbuf = wb + 4ull * DM * DM;              // [B][H][S][HD]
  unsigned short* kbuf = qbuf + (size_t)MROWS * DM;
  unsigned short* vbuf = kbuf + (size_t)MROWS * DM;
  float2* rope = (float2*)(vbuf + (size_t)MROWS * DM);     // [SEQ][512]

  convert_kernel<<<2048, 256, 0, stream>>>(x, xb, MROWS * DM);
  convert_kernel<<<256, 256, 0, stream>>>(Wq, wb, DM * DM);
  convert_kernel<<<256, 256, 0, stream>>>(Wk, wb + DM * DM, DM * DM);
  convert_kernel<<<256, 256, 0, stream>>>(Wv, wb + 2 * DM * DM, DM * DM);
  convert_kernel<<<256, 256, 0, stream>>>(Wo, wb + 3 * DM * DM, DM * DM);
  rope_table_kernel<<<(SEQ * 512 + 255) / 256, 256, 0, stream>>>(rope);

  // QKV projection: M=32768, N=3072, K=1024  (128 x 12 = 1536 blocks)
  gemm256_kernel<0><<<(MROWS / 256) * (3 * DM / 256), 512, 0, stream>>>(
      xb, wb, bq, bk, bv, rope, qbuf, kbuf, vbuf, nullptr, 3 * DM / 256);

  // attention per (b,h); writes vals (bf16) into xb buffer
  attn_kernel<<<BATCH * NH, 256, 0, stream>>>(qbuf, kbuf, vbuf, xb);

  // O projection: M=32768, N=1024, K=1024 -> fp32 out  (128 x 4 = 512 blocks)
  gemm256_kernel<1><<<(MROWS / 256) * (DM / 256), 512, 0, stream>>>(
      xb, wb + 3ull * DM * DM, bo, nullptr, nullptr, nullptr,
      nullptr, nullptr, nullptr, out, DM / 256);
}

// Round 3
// 470.129 us; speedup vs baseline: 1.1333x; 1.1333x over previous
//
#include <hip/hip_runtime.h>
#include <cstdint>
#include <cstddef>

#define DEVFN __device__ __forceinline__

typedef __attribute__((ext_vector_type(8))) __bf16 bf16x8;
typedef __attribute__((ext_vector_type(4))) float f32x4;
typedef __attribute__((ext_vector_type(16))) float f32x16;

static constexpr int DM = 1024;
static constexpr int NH = 16;
static constexpr int HD = 64;
static constexpr int BATCH = 512;
static constexpr int SEQ = 64;
static constexpr int MROWS = BATCH * SEQ;   // 32768
static constexpr int KDIM = DM;             // 1024

DEVFN unsigned short f2bf(float f) {
  unsigned u = __builtin_bit_cast(unsigned, f);
  u += 0x7fffu + ((u >> 16) & 1u);   // RNE
  return (unsigned short)(u >> 16);
}

DEVFN void gload_lds16(const void* g, void* l) {
  // async global->LDS, 16B per lane; LDS dest = wave-uniform base + lane*16B
  __builtin_amdgcn_global_load_lds(
      (__attribute__((address_space(1))) const void*)g,
      (__attribute__((address_space(3))) void*)l, 16, 0, 0);
}

// ------- one-shot fp32 -> bf16 convert of x + Wq|Wk|Wv|Wo into xb|wb -------
__global__ void convert_all_kernel(const float* __restrict__ x,
                                   const float* __restrict__ w0,
                                   const float* __restrict__ w1,
                                   const float* __restrict__ w2,
                                   const float* __restrict__ w3,
                                   unsigned short* __restrict__ dst) {
  const size_t NX = (size_t)MROWS * DM;          // 33.5M
  const size_t NTOT = NX + 4ull * DM * DM;       // +4M
  size_t i = ((size_t)blockIdx.x * blockDim.x + threadIdx.x) * 4;
  const size_t stride = (size_t)gridDim.x * blockDim.x * 4;
  for (; i < NTOT; i += stride) {
    const float* s;
    size_t off;
    if (i < NX) { s = x; off = i; }
    else {
      size_t j = i - NX;
      const int seg = (int)(j >> 20);
      off = j & ((1u << 20) - 1);
      s = (seg == 0) ? w0 : (seg == 1) ? w1 : (seg == 2) ? w2 : w3;
    }
    float4 f = *reinterpret_cast<const float4*>(s + off);
    ushort4 o;
    o.x = f2bf(f.x); o.y = f2bf(f.y); o.z = f2bf(f.z); o.w = f2bf(f.w);
    *reinterpret_cast<ushort4*>(dst + i) = o;
  }
}

// ---------------- RoPE cos/sin table: [SEQ][512] float2 ---------------------
__global__ void rope_table_kernel(float2* __restrict__ tab) {
  int idx = blockIdx.x * blockDim.x + threadIdx.x;
  if (idx >= SEQ * 512) return;
  int s = idx >> 9, i = idx & 511;
  float inv_freq = exp2f(-(float)i * (13.287712379549449f / 512.0f));
  float ang = (float)s * inv_freq;
  tab[idx] = make_float2(cosf(ang), sinf(ang));
}

// ---------------- 128x128 GEMM, BK=64, 4 waves, 32x32x16 MFMA ---------------
// C[M][N] = A[M][K] * B[N][K]^T (+epilogue)
// MODE 0: QKV projection (N=3072): bias + RoPE on q,k; bf16 scatter to
//         q/k/v buffers [B][H][S][HD].
// MODE 1: O projection (N=1024): +bias, fp32 store.
// LDS 16B-slot XOR swizzle: slot ^= (row&7); applied on the pre-swizzled
// global source (global_load_lds writes linearly) and on every ds_read.
template <int MODE>
__global__ __launch_bounds__(256, 2)
void gemm128_kernel(const unsigned short* __restrict__ A,
                    const unsigned short* __restrict__ Bw,
                    const float* __restrict__ bias0,
                    const float* __restrict__ bias1,
                    const float* __restrict__ bias2,
                    const float2* __restrict__ rope,
                    unsigned short* __restrict__ qb,
                    unsigned short* __restrict__ kb,
                    unsigned short* __restrict__ vb,
                    float* __restrict__ outf,
                    int Ntiles) {
  __shared__ __align__(16) unsigned short sA[128 * 64];
  __shared__ __align__(16) unsigned short sB[128 * 64];

  // T1: XCD-aware bijective swizzle (grid % 8 == 0 in both modes)
  const int cpx = gridDim.x >> 3;
  const int bid = (blockIdx.x & 7) * cpx + (blockIdx.x >> 3);
  const int bm = bid / Ntiles, bn = bid % Ntiles;
  const int m0 = bm * 128, n0 = bn * 128;

  const int tid = threadIdx.x;
  const int wave = tid >> 6, lane = tid & 63;
  const int wm = wave >> 1, wn = wave & 1;   // 2x2 waves; 64x64 out per wave

  // staging: pre-swizzled global source, linear LDS dest
  const int srow = tid >> 3;                       // 0..31
  const int scol = ((tid & 7) ^ (srow & 7)) * 8;   // swizzled k-slot (ushorts)
  const unsigned short* aB = A + ((size_t)m0 + srow) * KDIM + scol;
  const unsigned short* bB = Bw + ((size_t)n0 + srow) * KDIM + scol;

  f32x16 acc[2][2] = {};

  const int rA0 = wm * 64 + (lane & 31);
  const int rB0 = wn * 64 + (lane & 31);
  const int kq = (lane >> 5) * 8;                  // k sub-slot (ushorts)

  for (int t = 0; t < KDIM / 64; ++t) {
    const int k0 = t * 64;
#pragma unroll
    for (int p = 0; p < 4; ++p) {
      gload_lds16(aB + ((size_t)p * 32) * KDIM + k0, &sA[p * 2048 + wave * 512]);
      gload_lds16(bB + ((size_t)p * 32) * KDIM + k0, &sB[p * 2048 + wave * 512]);
    }
    __syncthreads();
#pragma unroll
    for (int ks = 0; ks < 4; ++ks) {
      const int kb16 = ks * 16 + kq;
      bf16x8 a[2], b[2];
#pragma unroll
      for (int f = 0; f < 2; ++f) {
        const int r = rA0 + f * 32;
        a[f] = *reinterpret_cast<const bf16x8*>(&sA[r * 64 + (kb16 ^ ((r & 7) * 8))]);
      }
#pragma unroll
      for (int g = 0; g < 2; ++g) {
        const int r = rB0 + g * 32;
        b[g] = *reinterpret_cast<const bf16x8*>(&sB[r * 64 + (kb16 ^ ((r & 7) * 8))]);
      }
#pragma unroll
      for (int f = 0; f < 2; ++f)
#pragma unroll
        for (int g = 0; g < 2; ++g)
          acc[f][g] = __builtin_amdgcn_mfma_f32_32x32x16_bf16(
              a[f], b[g], acc[f][g], 0, 0, 0);
    }
    __syncthreads();
  }

  // epilogue; 32x32 C/D layout: col=lane&31, row=(reg&3)+8*(reg>>2)+4*(lane>>5)
#pragma unroll
  for (int f = 0; f < 2; ++f) {
#pragma unroll
    for (int g = 0; g < 2; ++g) {
#pragma unroll
      for (int reg = 0; reg < 16; ++reg) {
        const int rloc = (reg & 3) + 8 * (reg >> 2) + 4 * (lane >> 5);
        const int row = m0 + wm * 64 + f * 32 + rloc;
        const int col = n0 + wn * 64 + g * 32 + (lane & 31);
        float v = acc[f][g][reg];
        if (MODE == 0) {
          const int id = col >> 10;        // 0=q 1=k 2=v (block-uniform)
          const int c = col & 1023;
          const float* bp = (id == 0) ? bias0 : (id == 1 ? bias1 : bias2);
          v += bp[c];
          const int si = row & 63;
          if (id < 2) {
            // RoPE: col pair (2i,2i+1) lives in lanes (l, l^1)
            const float p = __shfl_xor(v, 1);
            const float2 cs = rope[(si << 9) + (c >> 1)];
            v = v * cs.x + ((lane & 1) ? p * cs.y : -p * cs.y);
          }
          const int bi = row >> 6;
          const int h = c >> 6, dh = c & 63;
          const size_t off = (((size_t)bi * NH + h) * SEQ + si) * HD + dh;
          const unsigned short bfv = f2bf(v);
          if (id == 0) qb[off] = bfv;
          else if (id == 1) kb[off] = bfv;
          else vb[off] = bfv;
        } else {
          outf[(size_t)row * DM + col] = v + bias0[col];
        }
      }
    }
  }
}

// ---------------- attention: one block per (b,h); S=64, HD=64 ---------------
__global__ __launch_bounds__(256, 4)
void attn_kernel(const unsigned short* __restrict__ qb,
                 const unsigned short* __restrict__ kbuf,
                 const unsigned short* __restrict__ vbuf,
                 unsigned short* __restrict__ vals) {
  __shared__ __align__(16) unsigned short sQ[64 * 64];
  __shared__ __align__(16) unsigned short sK[64 * 64];
  __shared__ __align__(16) unsigned short sV[64 * 64];
  __shared__ __align__(16) unsigned short sP[64 * 64];
  const int bh = blockIdx.x;              // b*NH + h
  const int t = threadIdx.x, wave = t >> 6, lane = t & 63;
  const size_t base = (size_t)bh * 4096;

#pragma unroll
  for (int is = 0; is < 2; ++is) {
    const size_t go = base + is * 2048 + wave * 512 + (size_t)lane * 8;
    const int lo = is * 2048 + wave * 512;
    gload_lds16(qb + go, &sQ[lo]);
    gload_lds16(kbuf + go, &sK[lo]);
    gload_lds16(vbuf + go, &sV[lo]);
  }
  __syncthreads();

  // S = Q K^T : wave owns 16 q-rows; 4 col-frags cover 64 keys
  f32x4 sacc[4] = {};
#pragma unroll
  for (int kk = 0; kk < 2; ++kk) {
    const int krow = kk * 32 + (lane >> 4) * 8;
    const bf16x8 aq = *reinterpret_cast<const bf16x8*>(
        &sQ[(wave * 16 + (lane & 15)) * 64 + krow]);
#pragma unroll
    for (int ni = 0; ni < 4; ++ni) {
      const bf16x8 bkf = *reinterpret_cast<const bf16x8*>(
          &sK[(ni * 16 + (lane & 15)) * 64 + krow]);
      sacc[ni] = __builtin_amdgcn_mfma_f32_16x16x32_bf16(aq, bkf, sacc[ni], 0, 0, 0);
    }
  }
#pragma unroll
  for (int ni = 0; ni < 4; ++ni) sacc[ni] *= 0.125f;   // 1/sqrt(64)

  // softmax across 64 cols: in-lane over 4 frags, then shfl-xor over 16 lanes
#pragma unroll
  for (int r = 0; r < 4; ++r) {
    float mx = sacc[0][r];
#pragma unroll
    for (int ni = 1; ni < 4; ++ni) mx = fmaxf(mx, sacc[ni][r]);
#pragma unroll
    for (int off = 8; off; off >>= 1) mx = fmaxf(mx, __shfl_xor(mx, off));
    float e[4]; float sum = 0.f;
#pragma unroll
    for (int ni = 0; ni < 4; ++ni) { e[ni] = __expf(sacc[ni][r] - mx); sum += e[ni]; }
#pragma unroll
    for (int off = 8; off; off >>= 1) sum += __shfl_xor(sum, off);
    const float inv = 1.0f / sum;
    const int rowl = wave * 16 + (lane >> 4) * 4 + r;
#pragma unroll
    for (int ni = 0; ni < 4; ++ni)
      sP[rowl * 64 + ni * 16 + (lane & 15)] = f2bf(e[ni] * inv);
  }
  __syncthreads();

  // vals = P V
  f32x4 vacc[4] = {};
#pragma unroll
  for (int kk = 0; kk < 2; ++kk) {
    const int kb0 = kk * 32 + (lane >> 4) * 8;
    const bf16x8 ap = *reinterpret_cast<const bf16x8*>(
        &sP[(wave * 16 + (lane & 15)) * 64 + kb0]);
#pragma unroll
    for (int ni = 0; ni < 4; ++ni) {
      bf16x8 bvv;
      const int dh = ni * 16 + (lane & 15);
#pragma unroll
      for (int i = 0; i < 8; ++i)
        bvv[i] = __builtin_bit_cast(__bf16, sV[(kb0 + i) * 64 + dh]);
      vacc[ni] = __builtin_amdgcn_mfma_f32_16x16x32_bf16(ap, bvv, vacc[ni], 0, 0, 0);
    }
  }

  // store vals bf16 into [MROWS][DM] layout (row=b*64+s, col=h*64+dh)
  const int b = bh >> 4, h = bh & 15;
#pragma unroll
  for (int ni = 0; ni < 4; ++ni) {
#pragma unroll
    for (int r = 0; r < 4; ++r) {
      const int si = wave * 16 + (lane >> 4) * 4 + r;
      const int dh = ni * 16 + (lane & 15);
      vals[((size_t)b * SEQ + si) * DM + h * HD + dh] = f2bf(vacc[ni][r]);
    }
  }
}

// ---------------------------------------------------------------------------
extern "C" void kernel_launch(void* const* d_in, const int* in_sizes, int n_in,
                              void* d_out, int out_size, void* d_ws, size_t ws_size,
                              hipStream_t stream) {
  (void)in_sizes; (void)n_in; (void)out_size; (void)ws_size;
  const float* x  = (const float*)d_in[0];
  const float* Wq = (const float*)d_in[1];
  const float* bq = (const float*)d_in[2];
  const float* Wk = (const float*)d_in[3];
  const float* bk = (const float*)d_in[4];
  const float* Wv = (const float*)d_in[5];
  const float* bv = (const float*)d_in[6];
  const float* Wo = (const float*)d_in[7];
  const float* bo = (const float*)d_in[8];
  float* out = (float*)d_out;

  // ws layout (bf16 buffers), total ~277 MB
  unsigned short* xb   = (unsigned short*)d_ws;            // x bf16; later reused for vals
  unsigned short* wb   = xb + (size_t)MROWS * DM;          // Wq|Wk|Wv|Wo bf16, [4096][1024]
  unsigned short* qbuf = wb + 4ull * DM * DM;              // [B][H][S][HD]
  unsigned short* kbuf = qbuf + (size_t)MROWS * DM;
  unsigned short* vbuf = kbuf + (size_t)MROWS * DM;
  float2* rope = (float2*)(vbuf + (size_t)MROWS * DM);     // [SEQ][512]

  convert_all_kernel<<<2048, 256, 0, stream>>>(x, Wq, Wk, Wv, Wo, xb);
  rope_table_kernel<<<(SEQ * 512 + 255) / 256, 256, 0, stream>>>(rope);

  // QKV projection: M=32768, N=3072, K=1024  (256 x 24 = 6144 blocks)
  gemm128_kernel<0><<<(MROWS / 128) * (3 * DM / 128), 256, 0, stream>>>(
      xb, wb, bq, bk, bv, rope, qbuf, kbuf, vbuf, nullptr, 3 * DM / 128);

  // attention per (b,h); writes vals (bf16) into xb buffer
  attn_kernel<<<BATCH * NH, 256, 0, stream>>>(qbuf, kbuf, vbuf, xb);

  // O projection: M=32768, N=1024, K=1024 -> fp32 out  (256 x 8 = 2048 blocks)
  gemm128_kernel<1><<<(MROWS / 128) * (DM / 128), 256, 0, stream>>>(
      xb, wb + 3ull * DM * DM, bo, nullptr, nullptr, nullptr,
      nullptr, nullptr, nullptr, out, DM / 128);
}